// Round 11
// baseline (322.301 us; speedup 1.0000x reference)
//
#include <hip/hip_runtime.h>
#include <hip/hip_fp16.h>

#define N_NODES 50000
#define N_EDGES 1600000
#define CAP 160   // bucket capacity; in-degree ~ Poisson(32), P(>160) ~ 1e-56

typedef short bf16x8 __attribute__((ext_vector_type(8)));
typedef float f32x4  __attribute__((ext_vector_type(4)));
typedef float f32x2  __attribute__((ext_vector_type(2)));
typedef unsigned u32x4 __attribute__((ext_vector_type(4)));

__device__ inline unsigned f2bf(float f) {   // RNE f32 -> bf16 (low 16 bits)
    union { float f; unsigned u; } v; v.f = f;
    unsigned r = v.u + 0x7fff + ((v.u >> 16) & 1);
    return r >> 16;
}

// ---- fp8 e4m3 pack/unpack via gfx950 HW converters (OCP on gfx950) --------
__device__ inline unsigned pack_fp8x4(float a, float b, float c, float d) {
#if __has_builtin(__builtin_amdgcn_cvt_pk_fp8_f32)
    unsigned p = (unsigned)__builtin_amdgcn_cvt_pk_fp8_f32(a, b, 0, false);
    p = (unsigned)__builtin_amdgcn_cvt_pk_fp8_f32(c, d, (int)p, true);
    return p;
#else   // e5m2 fallback: top byte of f16 with RNE
    unsigned h, b0, b1, b2, b3;
    h = __half_as_ushort(__float2half(a)); b0 = ((h + 0x7f + ((h >> 8) & 1)) >> 8) & 0xff;
    h = __half_as_ushort(__float2half(b)); b1 = ((h + 0x7f + ((h >> 8) & 1)) >> 8) & 0xff;
    h = __half_as_ushort(__float2half(c)); b2 = ((h + 0x7f + ((h >> 8) & 1)) >> 8) & 0xff;
    h = __half_as_ushort(__float2half(d)); b3 = ((h + 0x7f + ((h >> 8) & 1)) >> 8) & 0xff;
    return b0 | (b1 << 8) | (b2 << 16) | (b3 << 24);
#endif
}
__device__ inline float4 unpack_fp8x4(unsigned u) {
#if __has_builtin(__builtin_amdgcn_cvt_pk_f32_fp8)
    f32x2 lo = __builtin_amdgcn_cvt_pk_f32_fp8((int)u, false);
    f32x2 hi = __builtin_amdgcn_cvt_pk_f32_fp8((int)u, true);
    return make_float4(lo[0], lo[1], hi[0], hi[1]);
#else   // e5m2 fallback
    __half_raw h0; h0.x = (unsigned short)((u & 0xff) << 8);
    __half_raw h1; h1.x = (unsigned short)(((u >> 8) & 0xff) << 8);
    __half_raw h2; h2.x = (unsigned short)(((u >> 16) & 0xff) << 8);
    __half_raw h3; h3.x = (unsigned short)(((u >> 24) & 0xff) << 8);
    return make_float4(__half2float(h0), __half2float(h1),
                       __half2float(h2), __half2float(h3));
#endif
}

// ---------------------------------------------------------------------------
__global__ __launch_bounds__(256) void zero_cursors_kernel(int* __restrict__ p) {
    int i = blockIdx.x * 256 + threadIdx.x;
    if (i < N_NODES) p[i] = 0;
}

// Direct binning of edge IDS (4B each): cursors end up holding the degree.
__global__ __launch_bounds__(256) void bin_direct_kernel(
    const int* __restrict__ receivers,
    int* __restrict__ cursors,
    int* __restrict__ edge_ids)       // [N_NODES][CAP]
{
    int e = blockIdx.x * 256 + threadIdx.x;
    if (e < N_EDGES) {
        int r = receivers[e];
        int p = atomicAdd(&cursors[r], 1);
        if (p < CAP) edge_ids[(size_t)r * CAP + p] = e;
    }
}

// Sequential f32 -> fp8 conversion of the WHOLE edge matrix (102.4 MB out,
// L3-resident for the immediately-following gather). Non-temporal loads on
// the 410MB f32 stream to avoid evicting the fp8 output from L3.
__global__ __launch_bounds__(256) void convert_fp8_kernel(
    const float* __restrict__ src,    // edge_feats
    u32x4* __restrict__ dst)          // fp8, 16B per thread-iter
{
    const int NQ = (N_EDGES * 64) / 16;       // 6,400,000 groups of 16 floats
    int idx = blockIdx.x * 256 + threadIdx.x;
    int stride = gridDim.x * 256;
    const f32x4* s4 = (const f32x4*)src;
    for (int i = idx; i < NQ; i += stride) {
        f32x4 a = __builtin_nontemporal_load(&s4[(size_t)i * 4 + 0]);
        f32x4 b = __builtin_nontemporal_load(&s4[(size_t)i * 4 + 1]);
        f32x4 c = __builtin_nontemporal_load(&s4[(size_t)i * 4 + 2]);
        f32x4 d = __builtin_nontemporal_load(&s4[(size_t)i * 4 + 3]);
        u32x4 o;
        o[0] = pack_fp8x4(a[0], a[1], a[2], a[3]);
        o[1] = pack_fp8x4(b[0], b[1], b[2], b[3]);
        o[2] = pack_fp8x4(c[0], c[1], c[2], c[3]);
        o[3] = pack_fp8x4(d[0], d[1], d[2], d[3]);
        dst[i] = o;                            // normal store: keep in L3
    }
}

// ---------------------------------------------------------------------------
// Fused gather + MLP. 512 threads (8 waves), 32 nodes/block.
// Gather: wave w owns 4 nodes; 64 edge-ids preloaded per coalesced read,
// broadcast via UNCONDITIONAL shfl (R6 lesson: never shfl under divergence).
// Each row read = one random 64B fp8 line (mostly L3-resident), 4 rows per
// wave instruction (g=row group, q=4B slice), unroll 8. f32 accumulate,
// mean -> swizzled bf16 x-tile. MLP per m89 layouts.
__global__ __launch_bounds__(512) void fused_gather_mlp_kernel(
    const unsigned char* __restrict__ fp8e,   // [N_EDGES][64] fp8
    const int*   __restrict__ edge_ids,       // [N_NODES][CAP]
    const int*   __restrict__ counts,
    const float* __restrict__ node_feats,
    const short* __restrict__ W1p, const float* __restrict__ b1,
    const short* __restrict__ W2p, const float* __restrict__ b2,
    float*       __restrict__ out)
{
    __shared__ uint4 xbuf[512];    // 8KB : x[32][128] bf16, swizzled
    __shared__ uint4 hbuf[1024];   // 16KB: h[32][256] bf16, swizzled
    char* xb = (char*)xbuf;
    char* hb = (char*)hbuf;
    const int t = threadIdx.x;
    const int l = t & 63;
    const int w = t >> 6;          // wave 0..7
    const int g = l >> 4;          // row group 0..3
    const int q = l & 15;          // 4B slice
    const int node0 = blockIdx.x * 32;

    // ---- stage node_feats half of x: 512 threads = 32 nodes x 16 q ----
    {
        int node = t >> 4;
        int qq = t & 15;
        int nl = node0 + node;
        float4 v = make_float4(0.f, 0.f, 0.f, 0.f);
        if (nl < N_NODES) v = ((const float4*)(node_feats + (size_t)nl * 64))[qq];
        unsigned lo = f2bf(v.x) | (f2bf(v.y) << 16);
        unsigned hi = f2bf(v.z) | (f2bf(v.w) << 16);
        int byte = node * 256 + 128 + qq * 8;
        byte ^= (node & 7) << 4;
        *(uint2*)(xb + byte) = make_uint2(lo, hi);
    }

    // ---- gather (segment mean): wave w owns local nodes w*4 .. w*4+3 ----
    for (int n = 0; n < 4; ++n) {
        int nodeLocal = w * 4 + n;
        int node = node0 + nodeLocal;
        int cnt = (node < N_NODES) ? min(counts[node], CAP) : 0;
        const int* ids = edge_ids + (size_t)node * CAP;
        float4 acc0 = make_float4(0.f, 0.f, 0.f, 0.f);
        float4 acc1 = make_float4(0.f, 0.f, 0.f, 0.f);
        for (int base = 0; base < cnt; base += 64) {
            int m = min(cnt - base, 64);
            int myid = (l < m) ? ids[base + l] : 0;     // coalesced 256B
            for (int half = 0; half < m; half += 32) {
                #pragma unroll
                for (int u = 0; u < 8; ++u) {
                    int r = half + u * 4 + g;           // r <= 63 always
                    int e = __shfl(myid, r);            // ALL lanes active
                    if (r < m) {
                        unsigned uv = *(const unsigned*)(fp8e + (size_t)e * 64 + q * 4);
                        float4 f = unpack_fp8x4(uv);
                        if (u & 1) { acc1.x += f.x; acc1.y += f.y;
                                     acc1.z += f.z; acc1.w += f.w; }
                        else       { acc0.x += f.x; acc0.y += f.y;
                                     acc0.z += f.z; acc0.w += f.w; }
                    }
                }
            }
        }
        float4 acc = make_float4(acc0.x + acc1.x, acc0.y + acc1.y,
                                 acc0.z + acc1.z, acc0.w + acc1.w);
        acc.x += __shfl_xor(acc.x, 16); acc.y += __shfl_xor(acc.y, 16);
        acc.z += __shfl_xor(acc.z, 16); acc.w += __shfl_xor(acc.w, 16);
        acc.x += __shfl_xor(acc.x, 32); acc.y += __shfl_xor(acc.y, 32);
        acc.z += __shfl_xor(acc.z, 32); acc.w += __shfl_xor(acc.w, 32);
        if (g == 0) {                 // cnt==0 (incl. node>=N) writes zeros
            float inv = 1.f / fmaxf((float)cnt, 1.f);
            unsigned lo = f2bf(acc.x * inv) | (f2bf(acc.y * inv) << 16);
            unsigned hi = f2bf(acc.z * inv) | (f2bf(acc.w * inv) << 16);
            int byte = nodeLocal * 256 + q * 8;
            byte ^= (nodeLocal & 7) << 4;
            *(uint2*)(xb + byte) = make_uint2(lo, hi);
        }
    }
    __syncthreads();

    // ---- GEMM1: h = relu(x @ W1 + b1); wave w owns nt = 2w, 2w+1 ----
    bf16x8 afr[2][4];
    #pragma unroll
    for (int m = 0; m < 2; ++m)
        #pragma unroll
        for (int c = 0; c < 4; ++c) {
            int row  = m * 16 + (l & 15);
            int byte = row * 256 + c * 64 + (l >> 4) * 16;
            byte ^= (row & 7) << 4;
            afr[m][c] = *(const bf16x8*)(xb + byte);
        }
    #pragma unroll
    for (int i = 0; i < 2; ++i) {
        int nt = w * 2 + i;
        bf16x8 bfr[4];
        #pragma unroll
        for (int c = 0; c < 4; ++c)
            bfr[c] = *(const bf16x8*)(W1p + ((size_t)(nt * 4 + c) * 64 + l) * 8);
        float bb = b1[nt * 16 + (l & 15)];
        #pragma unroll
        for (int m = 0; m < 2; ++m) {
            f32x4 acc = {0.f, 0.f, 0.f, 0.f};
            #pragma unroll
            for (int c = 0; c < 4; ++c)
                acc = __builtin_amdgcn_mfma_f32_16x16x32_bf16(afr[m][c], bfr[c], acc, 0, 0, 0);
            #pragma unroll
            for (int r = 0; r < 4; ++r) {
                int row = m * 16 + (l >> 4) * 4 + r;
                int col = nt * 16 + (l & 15);
                unsigned hv = f2bf(fmaxf(acc[r] + bb, 0.f));
                int byte = row * 512 + col * 2;
                byte ^= (row & 7) << 4;
                *(unsigned short*)(hb + byte) = (unsigned short)hv;
            }
        }
    }
    __syncthreads();

    // ---- GEMM2: out = h @ W2 + b2; wave w -> (mt = w>>2, nt = w&3) ----
    {
        const int mt = w >> 2;
        const int nt = w & 3;
        bf16x8 a2[8];
        #pragma unroll
        for (int c = 0; c < 8; ++c) {
            int row  = mt * 16 + (l & 15);
            int byte = row * 512 + c * 64 + (l >> 4) * 16;
            byte ^= (row & 7) << 4;
            a2[c] = *(const bf16x8*)(hb + byte);
        }
        bf16x8 bfr[8];
        #pragma unroll
        for (int c = 0; c < 8; ++c)
            bfr[c] = *(const bf16x8*)(W2p + ((size_t)(nt * 8 + c) * 64 + l) * 8);
        f32x4 acc = {0.f, 0.f, 0.f, 0.f};
        #pragma unroll
        for (int c = 0; c < 8; ++c)
            acc = __builtin_amdgcn_mfma_f32_16x16x32_bf16(a2[c], bfr[c], acc, 0, 0, 0);
        float bb = b2[nt * 16 + (l & 15)];
        #pragma unroll
        for (int r = 0; r < 4; ++r) {
            int node = node0 + mt * 16 + (l >> 4) * 4 + r;
            if (node < N_NODES)
                out[(size_t)node * 64 + nt * 16 + (l & 15)] = acc[r] + bb;
        }
    }
}

// ---------------------------------------------------------------------------
// Pre-pack W1/W2 to bf16 in MFMA B-fragment-linear order:
// frag (nt, c): lane l, elem j  =  W[k = c*32 + (l>>4)*8 + j][col = nt*16 + (l&15)]
__global__ __launch_bounds__(256) void prepack_kernel(
    const float* __restrict__ W1, const float* __restrict__ W2,
    short* __restrict__ W1p, short* __restrict__ W2p)
{
    int t = blockIdx.x * 256 + threadIdx.x;
    if (t < 4096) {                   // W1: 16 nt x 4 c x 64 lanes
        int c = (t >> 6) & 3, nt = t >> 8, l = t & 63;
        short tmp[8];
        #pragma unroll
        for (int j = 0; j < 8; ++j) {
            int k = c * 32 + (l >> 4) * 8 + j;
            tmp[j] = (short)f2bf(W1[k * 256 + nt * 16 + (l & 15)]);
        }
        #pragma unroll
        for (int j = 0; j < 8; ++j) W1p[(size_t)t * 8 + j] = tmp[j];
    } else if (t < 6144) {            // W2: 4 nt x 8 c x 64 lanes
        int u = t - 4096;
        int c = (u >> 6) & 7, nt = u >> 9, l = u & 63;
        short tmp[8];
        #pragma unroll
        for (int j = 0; j < 8; ++j) {
            int k = c * 32 + (l >> 4) * 8 + j;
            tmp[j] = (short)f2bf(W2[k * 64 + nt * 16 + (l & 15)]);
        }
        #pragma unroll
        for (int j = 0; j < 8; ++j) W2p[(size_t)u * 8 + j] = tmp[j];
    }
}

// ---------------------------------------------------------------------------
// Fallback path (tiny ws): atomic scatter + normalize + f32 MLP.
__global__ __launch_bounds__(256) void scatter_kernel(
    const float* __restrict__ edge_feats, const int* __restrict__ receivers,
    float* __restrict__ agg, float* __restrict__ fcounts)
{
    int gid = blockIdx.x * 256 + threadIdx.x;
    int e = gid >> 6, d = gid & 63;
    if (e >= N_EDGES) return;
    int r = receivers[e];
    atomicAdd(&agg[(size_t)r * 64 + d], edge_feats[(size_t)e * 64 + d]);
    if (d == 0) atomicAdd(&fcounts[r], 1.0f);
}
__global__ __launch_bounds__(256) void normalize_kernel(
    float* __restrict__ agg, const float* __restrict__ fcounts)
{
    int i = blockIdx.x * 256 + threadIdx.x;
    if (i < N_NODES * 64) agg[i] /= fmaxf(fcounts[i >> 6], 1.0f);
}
__global__ __launch_bounds__(256) void mlp_f32_kernel(
    const float* __restrict__ node_feats,
    const float* __restrict__ W1, const float* __restrict__ b1,
    const float* __restrict__ W2, const float* __restrict__ b2,
    float*       __restrict__ agg_out)
{
    __shared__ float x[16][128];
    __shared__ float h[16][256];
    const int t = threadIdx.x;
    const int node0 = blockIdx.x * 16;
    for (int i = t; i < 2048; i += 256) {
        int n = i >> 7, k = i & 127;
        int node = node0 + n;
        float v = 0.f;
        if (node < N_NODES)
            v = (k < 64) ? agg_out[(size_t)node * 64 + k]
                         : node_feats[(size_t)node * 64 + (k - 64)];
        x[n][k] = v;
    }
    __syncthreads();
    {
        float acc[16];
        #pragma unroll
        for (int n = 0; n < 16; ++n) acc[n] = 0.f;
        for (int k = 0; k < 128; ++k) {
            float ww = W1[k * 256 + t];
            #pragma unroll
            for (int n = 0; n < 16; ++n) acc[n] += x[n][k] * ww;
        }
        float bb = b1[t];
        #pragma unroll
        for (int n = 0; n < 16; ++n) h[n][t] = fmaxf(acc[n] + bb, 0.f);
    }
    __syncthreads();
    {
        int c = t & 63, n0 = (t >> 6) * 4;
        float acc[4] = {0.f, 0.f, 0.f, 0.f};
        for (int k = 0; k < 256; ++k) {
            float ww = W2[k * 64 + c];
            #pragma unroll
            for (int i = 0; i < 4; ++i) acc[i] += h[n0 + i][k] * ww;
        }
        float bb = b2[c];
        #pragma unroll
        for (int i = 0; i < 4; ++i) {
            int node = node0 + n0 + i;
            if (node < N_NODES) agg_out[(size_t)node * 64 + c] = acc[i] + bb;
        }
    }
}

// ---------------------------------------------------------------------------
extern "C" void kernel_launch(void* const* d_in, const int* in_sizes, int n_in,
                              void* d_out, int out_size, void* d_ws, size_t ws_size,
                              hipStream_t stream) {
    const float* node_feats = (const float*)d_in[0];
    const float* edge_feats = (const float*)d_in[1];
    const int*   receivers  = (const int*)  d_in[2];
    const float* W1 = (const float*)d_in[3];
    const float* b1 = (const float*)d_in[4];
    const float* W2 = (const float*)d_in[5];
    const float* b2 = (const float*)d_in[6];
    float* out = (float*)d_out;

    // ws: W1p 64KB | W2p 32KB | cursors 200KB | edge_ids 32MB | fp8 102.4MB
    char* wsc = (char*)d_ws;
    short* W1p      = (short*)wsc;                        // 32768 elems
    short* W2p      = (short*)(wsc + 65536);              // 16384 elems
    int*   cursors  = (int*)  (wsc + 98304);              // [N_NODES]
    int*   edge_ids = (int*)  (wsc + 298496);             // [N_NODES][CAP]
    unsigned char* fp8e = (unsigned char*)(wsc + 298496 +
                         (size_t)N_NODES * CAP * sizeof(int));  // [N_EDGES][64]
    size_t need = 298496 + (size_t)N_NODES * CAP * sizeof(int)
                + (size_t)N_EDGES * 64;

    if (ws_size >= need) {
        prepack_kernel<<<24, 256, 0, stream>>>(W1, W2, W1p, W2p);
        zero_cursors_kernel<<<(N_NODES + 255) / 256, 256, 0, stream>>>(cursors);
        bin_direct_kernel<<<(N_EDGES + 255) / 256, 256, 0, stream>>>(
            receivers, cursors, edge_ids);
        // convert LAST before the gather so the fp8 array is L3-hot
        convert_fp8_kernel<<<2048, 256, 0, stream>>>(
            edge_feats, (u32x4*)fp8e);
        fused_gather_mlp_kernel<<<(N_NODES + 31) / 32, 512, 0, stream>>>(
            fp8e, edge_ids, cursors, node_feats, W1p, b1, W2p, b2, out);
    } else {
        float* fcounts = (float*)d_ws;
        hipMemsetAsync(d_out, 0, (size_t)N_NODES * 64 * sizeof(float), stream);
        hipMemsetAsync(fcounts, 0, N_NODES * sizeof(float), stream);
        scatter_kernel<<<(N_EDGES * 64) / 256, 256, 0, stream>>>(
            edge_feats, receivers, out, fcounts);
        normalize_kernel<<<(N_NODES * 64 + 255) / 256, 256, 0, stream>>>(out, fcounts);
        mlp_f32_kernel<<<(N_NODES + 15) / 16, 256, 0, stream>>>(
            node_feats, W1, b1, W2, b2, out);
    }
}